// Round 6
// baseline (2143.720 us; speedup 1.0000x reference)
//
#include <hip/hip_runtime.h>

#define BB 128
#define TT 1024
#define II 100
#define HH 200
#define MB 16          // batches per recurrence block -> 8 blocks
#define NTL 13         // ceil(200/16) j-tiles
#define KST 7          // ceil(200/32) k-steps
#define HSTR 232       // padded f16 row stride for H_lds
#define SUP 8          // steps per superstep (global-traffic pipeline depth)

typedef _Float16 half8  __attribute__((ext_vector_type(8)));
typedef _Float16 half4v __attribute__((ext_vector_type(4)));
typedef float    f32x4  __attribute__((ext_vector_type(4)));

// ---------------------------------------------------------------------------
// Phase 1: xp[r][j] = b_ih[j] + b_hh[j] + sum_i x[r][i] * W_ih[j][i]
// (unchanged — isolate the recurrence experiment)
// ---------------------------------------------------------------------------
__global__ __launch_bounds__(256, 1) void rnn_xproj(
    const float* __restrict__ x, const float* __restrict__ Wih,
    const float* __restrict__ bih, const float* __restrict__ bhh,
    float* __restrict__ hid)
{
    __shared__ __align__(16) float xs[128 * II];  // 51.2 KB
    const int tid = threadIdx.x;
    const int j = tid;
    const int jl = (j < HH) ? j : (HH - 1);

    float4 w[25];
    const float4* wrow = (const float4*)(Wih + jl * II);
#pragma unroll
    for (int kk = 0; kk < 25; ++kk) w[kk] = wrow[kk];
    const float bias = bih[jl] + bhh[jl];

    const long long r0 = (long long)blockIdx.x * 128;
    const float4* src = (const float4*)(x + r0 * II);
    float4* dst = (float4*)xs;
    for (int p = tid; p < 128 * II / 4; p += 256) dst[p] = src[p];
    __syncthreads();

    for (int row = 0; row < 128; ++row) {
        float a0 = 0.f, a1 = 0.f, a2 = 0.f, a3 = 0.f;
        const float4* xr = (const float4*)(xs + row * II);
#pragma unroll
        for (int kk = 0; kk < 25; ++kk) {
            float4 v = xr[kk];
            a0 += w[kk].x * v.x; a1 += w[kk].y * v.y;
            a2 += w[kk].z * v.z; a3 += w[kk].w * v.w;
        }
        if (j < HH)
            hid[(r0 + row) * HH + j] = bias + ((a0 + a1) + (a2 + a3));
    }
}

// ---------------------------------------------------------------------------
// Phase 2: MFMA recurrence with 8-step global-traffic pipeline.
// 8 blocks x 256 threads (4 waves, 1 wave/SIMD, 512-VGPR budget).
// xp(t) loaded into registers at step t-8; h(t) archived in fp16 registers
// and stored to global at step t+8. All global latency gets ~8 steps of
// slack; the per-step critical path is LDS + MFMA + epilogue only.
// ---------------------------------------------------------------------------
__global__ __launch_bounds__(256, 1) __attribute__((amdgpu_waves_per_eu(1, 1)))
void rnn_recur(const float* __restrict__ Whh, float* __restrict__ hid)
{
    __shared__ _Float16 hl[2][MB][HSTR];   // 14.8 KB double-buffered H (fp16)

    const int tid = threadIdx.x;
    const int wv  = tid >> 6;
    const int l   = tid & 63;
    const int m   = l & 15;     // batch index within group (B-col / C-col)
    const int kq  = l >> 4;     // k-subblock 0..3

    // ---- one-time: W_hh -> per-wave A-fragments in registers ----
    half8 wf[4][KST];
#pragma unroll
    for (int i = 0; i < 4; ++i) {
        const int nt = 4 * i + wv;
        const bool v = (nt < NTL);
        int j = 16 * nt + m; if (j > HH - 1) j = HH - 1;
#pragma unroll
        for (int ks = 0; ks < KST; ++ks) {
            const int k0 = 32 * ks + 8 * kq;
            half8 f;
#pragma unroll
            for (int e = 0; e < 8; ++e) f[e] = (_Float16)0.f;
            if (v && k0 < HH) {
                const float4 lo = *(const float4*)(Whh + j * HH + k0);
                const float4 hi = *(const float4*)(Whh + j * HH + k0 + 4);
                f[0] = (_Float16)lo.x; f[1] = (_Float16)lo.y;
                f[2] = (_Float16)lo.z; f[3] = (_Float16)lo.w;
                f[4] = (_Float16)hi.x; f[5] = (_Float16)hi.y;
                f[6] = (_Float16)hi.z; f[7] = (_Float16)hi.w;
            }
            wf[i][ks] = f;
        }
    }

    // per-i epilogue geometry
    int  j0a[4]; bool stv[4];
#pragma unroll
    for (int i = 0; i < 4; ++i) {
        const int nt = 4 * i + wv;
        j0a[i] = 16 * nt + 4 * kq;
        stv[i] = (nt < NTL) && (j0a[i] < HH);
    }

    // zero both H buffers (incl. k-padding columns)
    {
        int* zp = (int*)hl;
        for (int p = tid; p < (int)(sizeof(hl) / 4); p += 256) zp[p] = 0;
    }
    __syncthreads();

    const long long TTHH = (long long)TT * HH;
    float* mybase = hid + (long long)blockIdx.x * MB * TTHH + (long long)m * TTHH;

    // pipeline registers
    float4 xpb[SUP][4];     // xp for steps [ss*8 .. ss*8+7]
    half4v hreg[SUP][4];    // h archive, stored 8 steps late
    const half4v zpk = {(_Float16)0.f, (_Float16)0.f, (_Float16)0.f, (_Float16)0.f};
#pragma unroll
    for (int e = 0; e < SUP; ++e)
#pragma unroll
        for (int i = 0; i < 4; ++i) {
            hreg[e][i] = zpk;
            xpb[e][i] = stv[i] ? *(const float4*)(mybase + (long long)e * HH + j0a[i])
                               : make_float4(0.f, 0.f, 0.f, 0.f);
        }

    int cur = 0;
#pragma unroll 1
    for (int ss = 0; ss < TT / SUP; ++ss) {
        const bool notfirst = (ss > 0);
        const bool notlast  = (ss + 1 < TT / SUP);
#pragma unroll
        for (int e = 0; e < SUP; ++e) {
            const int t = ss * SUP + e;

            // B-fragments: H^T slices from LDS
            half8 bf[KST];
            const _Float16* hb = &hl[cur][m][0];
#pragma unroll
            for (int ks = 0; ks < KST; ++ks)
                bf[ks] = *(const half8*)(hb + 32 * ks + 8 * kq);

            // MFMA accumulate, even/odd ks chains (depth 4+3, 8-way ILP)
            f32x4 accE[4], accO[4];
#pragma unroll
            for (int i = 0; i < 4; ++i) {
                accE[i] = (f32x4){0.f, 0.f, 0.f, 0.f};
                accO[i] = (f32x4){0.f, 0.f, 0.f, 0.f};
            }
#pragma unroll
            for (int ks = 0; ks < KST; ks += 2)
#pragma unroll
                for (int i = 0; i < 4; ++i)
                    accE[i] = __builtin_amdgcn_mfma_f32_16x16x32_f16(
                        wf[i][ks], bf[ks], accE[i], 0, 0, 0);
#pragma unroll
            for (int ks = 1; ks < KST; ks += 2)
#pragma unroll
                for (int i = 0; i < 4; ++i)
                    accO[i] = __builtin_amdgcn_mfma_f32_16x16x32_f16(
                        wf[i][ks], bf[ks], accO[i], 0, 0, 0);

            // epilogue: h = relu(xp + acc); fp16 to next H buf + archive;
            // archived h(t-8) stored to global; xp(t+8) refill issued.
#pragma unroll
            for (int i = 0; i < 4; ++i) {
                if (!stv[i]) continue;
                const float h0 = fmaxf(accE[i][0] + accO[i][0] + xpb[e][i].x, 0.f);
                const float h1 = fmaxf(accE[i][1] + accO[i][1] + xpb[e][i].y, 0.f);
                const float h2 = fmaxf(accE[i][2] + accO[i][2] + xpb[e][i].z, 0.f);
                const float h3 = fmaxf(accE[i][3] + accO[i][3] + xpb[e][i].w, 0.f);
                half4v pk = {(_Float16)h0, (_Float16)h1, (_Float16)h2, (_Float16)h3};
                *(half4v*)&hl[cur ^ 1][m][j0a[i]] = pk;

                if (notfirst) {
                    half4v ov = hreg[e][i];
                    *(float4*)(mybase + (long long)(t - SUP) * HH + j0a[i]) =
                        make_float4((float)ov[0], (float)ov[1],
                                    (float)ov[2], (float)ov[3]);
                }
                hreg[e][i] = pk;

                if (notlast)
                    xpb[e][i] = *(const float4*)(mybase + (long long)(t + SUP) * HH + j0a[i]);
            }

            __syncthreads();   // H(t+1) visible; orders WAR on hl[cur]
            cur ^= 1;
        }
    }

    // flush: archived h for the last superstep (t = TT-8 .. TT-1)
#pragma unroll
    for (int e = 0; e < SUP; ++e)
#pragma unroll
        for (int i = 0; i < 4; ++i) {
            if (!stv[i]) continue;
            half4v ov = hreg[e][i];
            *(float4*)(mybase + (long long)(TT - SUP + e) * HH + j0a[i]) =
                make_float4((float)ov[0], (float)ov[1], (float)ov[2], (float)ov[3]);
        }
}

// ---------------------------------------------------------------------------
// Phase 3: o[r] = sum_j W_out[j]*h[r][j] + b_out. (unchanged)
// ---------------------------------------------------------------------------
__global__ __launch_bounds__(256) void rnn_out(
    const float* __restrict__ hid, const float* __restrict__ Wout,
    const float* __restrict__ bout, float* __restrict__ out)
{
    const int wave = threadIdx.x >> 6;
    const int lane = threadIdx.x & 63;

    float wv[4];
#pragma unroll
    for (int mi = 0; mi < 4; ++mi) {
        int idx = lane + 64 * mi;
        wv[mi] = (idx < HH) ? Wout[idx] : 0.f;
    }
    const float bo = bout[0];

    const long long rbase = (long long)blockIdx.x * 64;
#pragma unroll 1
    for (int rr = wave; rr < 64; rr += 4) {
        const float* hr = hid + (rbase + rr) * HH;
        float p = 0.f;
#pragma unroll
        for (int mi = 0; mi < 4; ++mi) {
            int idx = lane + 64 * mi;
            if (idx < HH) p += wv[mi] * hr[idx];
        }
#pragma unroll
        for (int off = 32; off; off >>= 1) p += __shfl_down(p, off, 64);
        if (lane == 0) out[rbase + rr] = p + bo;
    }
}

extern "C" void kernel_launch(void* const* d_in, const int* in_sizes, int n_in,
                              void* d_out, int out_size, void* d_ws, size_t ws_size,
                              hipStream_t stream)
{
    const float* x    = (const float*)d_in[0];  // [128,1024,100]
    const float* Wih  = (const float*)d_in[1];  // [200,100]
    const float* Whh  = (const float*)d_in[2];  // [200,200]
    const float* bih  = (const float*)d_in[3];  // [200]
    const float* bhh  = (const float*)d_in[4];  // [200]
    const float* Wout = (const float*)d_in[5];  // [1,200]
    const float* bout = (const float*)d_in[6];  // [1]

    float* out = (float*)d_out;                 // [128*1024] outputs first
    float* hid = out + (long long)BB * TT;      // [128*1024*200] hiddens

    rnn_xproj<<<(BB * TT) / 128, 256, 0, stream>>>(x, Wih, bih, bhh, hid);
    rnn_recur<<<BB / MB, 256, 0, stream>>>(Whh, hid);
    rnn_out<<<(BB * TT) / 64, 256, 0, stream>>>(hid, Wout, bout, out);
}

// Round 7
// 1909.233 us; speedup vs baseline: 1.1228x; 1.1228x over previous
//
#include <hip/hip_runtime.h>

#define BB 128
#define TT 1024
#define II 100
#define HH 200
#define MB 16          // batches per recurrence block -> 8 blocks
#define NTL 13         // ceil(200/16) j-tiles
#define KST 7          // ceil(200/32) k-steps
#define HSTR 232       // padded f16 row stride for H_lds

typedef _Float16 half8  __attribute__((ext_vector_type(8)));
typedef _Float16 half4v __attribute__((ext_vector_type(4)));
typedef float    f32x4  __attribute__((ext_vector_type(4)));

// ---------------------------------------------------------------------------
// Phase 1: xp[r][j] = b_ih[j] + b_hh[j] + sum_i x[r][i] * W_ih[j][i]
// (unchanged — isolate the recurrence experiment)
// ---------------------------------------------------------------------------
__global__ __launch_bounds__(256, 1) void rnn_xproj(
    const float* __restrict__ x, const float* __restrict__ Wih,
    const float* __restrict__ bih, const float* __restrict__ bhh,
    float* __restrict__ hid)
{
    __shared__ __align__(16) float xs[128 * II];  // 51.2 KB
    const int tid = threadIdx.x;
    const int j = tid;
    const int jl = (j < HH) ? j : (HH - 1);

    float4 w[25];
    const float4* wrow = (const float4*)(Wih + jl * II);
#pragma unroll
    for (int kk = 0; kk < 25; ++kk) w[kk] = wrow[kk];
    const float bias = bih[jl] + bhh[jl];

    const long long r0 = (long long)blockIdx.x * 128;
    const float4* src = (const float4*)(x + r0 * II);
    float4* dst = (float4*)xs;
    for (int p = tid; p < 128 * II / 4; p += 256) dst[p] = src[p];
    __syncthreads();

    for (int row = 0; row < 128; ++row) {
        float a0 = 0.f, a1 = 0.f, a2 = 0.f, a3 = 0.f;
        const float4* xr = (const float4*)(xs + row * II);
#pragma unroll
        for (int kk = 0; kk < 25; ++kk) {
            float4 v = xr[kk];
            a0 += w[kk].x * v.x; a1 += w[kk].y * v.y;
            a2 += w[kk].z * v.z; a3 += w[kk].w * v.w;
        }
        if (j < HH)
            hid[(r0 + row) * HH + j] = bias + ((a0 + a1) + (a2 + a3));
    }
}

// ---------------------------------------------------------------------------
// Phase 2: MFMA recurrence, raw-barrier version.
// 8 blocks x 256 threads (4 waves, 1 wave/SIMD, 512-VGPR budget).
// Hot-loop barrier is s_waitcnt lgkmcnt(0) + s_barrier ONLY: the LDS h
// exchange is the sole cross-thread dependency. xp loads (2-step prefetch,
// static ping-pong regs) and h stores are thread-private and stay in
// flight across the barrier; compiler emits counted vmcnt before use.
// ---------------------------------------------------------------------------
__global__ __launch_bounds__(256, 1) __attribute__((amdgpu_waves_per_eu(1, 1)))
void rnn_recur(const float* __restrict__ Whh, float* __restrict__ hid)
{
    __shared__ _Float16 hl[2][MB][HSTR];   // 14.8 KB double-buffered H (fp16)

    const int tid = threadIdx.x;
    const int wv  = tid >> 6;
    const int l   = tid & 63;
    const int m   = l & 15;     // batch index within group (B-col / C-col)
    const int kq  = l >> 4;     // k-subblock 0..3

    // ---- one-time: W_hh -> per-wave A-fragments in registers ----
    half8 wf[4][KST];
#pragma unroll
    for (int i = 0; i < 4; ++i) {
        const int nt = 4 * i + wv;
        const bool v = (nt < NTL);
        int j = 16 * nt + m; if (j > HH - 1) j = HH - 1;
#pragma unroll
        for (int ks = 0; ks < KST; ++ks) {
            const int k0 = 32 * ks + 8 * kq;
            half8 f;
#pragma unroll
            for (int e = 0; e < 8; ++e) f[e] = (_Float16)0.f;
            if (v && k0 < HH) {
                const float4 lo = *(const float4*)(Whh + j * HH + k0);
                const float4 hi = *(const float4*)(Whh + j * HH + k0 + 4);
                f[0] = (_Float16)lo.x; f[1] = (_Float16)lo.y;
                f[2] = (_Float16)lo.z; f[3] = (_Float16)lo.w;
                f[4] = (_Float16)hi.x; f[5] = (_Float16)hi.y;
                f[6] = (_Float16)hi.z; f[7] = (_Float16)hi.w;
            }
            wf[i][ks] = f;
        }
    }

    // per-i epilogue geometry
    int  j0a[4]; bool stv[4];
#pragma unroll
    for (int i = 0; i < 4; ++i) {
        const int nt = 4 * i + wv;
        j0a[i] = 16 * nt + 4 * kq;
        stv[i] = (nt < NTL) && (j0a[i] < HH);
    }

    // zero both H buffers (incl. k-padding columns)
    {
        int* zp = (int*)hl;
        for (int p = tid; p < (int)(sizeof(hl) / 4); p += 256) zp[p] = 0;
    }
    __syncthreads();

    const long long TTHH = (long long)TT * HH;
    float* mybase = hid + (long long)blockIdx.x * MB * TTHH + (long long)m * TTHH;

    // 2-step xp prefetch, statically indexed ping-pong
    float4 xpb[2][4];
#pragma unroll
    for (int e = 0; e < 2; ++e)
#pragma unroll
        for (int i = 0; i < 4; ++i)
            xpb[e][i] = stv[i] ? *(const float4*)(mybase + (long long)e * HH + j0a[i])
                               : make_float4(0.f, 0.f, 0.f, 0.f);

    int cur = 0;
#pragma unroll 1
    for (int t = 0; t < TT; t += 2) {
#pragma unroll
        for (int e = 0; e < 2; ++e) {
            // B-fragments: H^T slices from LDS
            half8 bf[KST];
            const _Float16* hb = &hl[cur][m][0];
#pragma unroll
            for (int ks = 0; ks < KST; ++ks)
                bf[ks] = *(const half8*)(hb + 32 * ks + 8 * kq);

            // MFMA accumulate, even/odd ks chains (8 independent chains)
            f32x4 accE[4], accO[4];
#pragma unroll
            for (int i = 0; i < 4; ++i) {
                accE[i] = (f32x4){0.f, 0.f, 0.f, 0.f};
                accO[i] = (f32x4){0.f, 0.f, 0.f, 0.f};
            }
#pragma unroll
            for (int ks = 0; ks < KST; ks += 2)
#pragma unroll
                for (int i = 0; i < 4; ++i)
                    accE[i] = __builtin_amdgcn_mfma_f32_16x16x32_f16(
                        wf[i][ks], bf[ks], accE[i], 0, 0, 0);
#pragma unroll
            for (int ks = 1; ks < KST; ks += 2)
#pragma unroll
                for (int i = 0; i < 4; ++i)
                    accO[i] = __builtin_amdgcn_mfma_f32_16x16x32_f16(
                        wf[i][ks], bf[ks], accO[i], 0, 0, 0);

            // epilogue: h = relu(xp + acc); fp16 -> next H buf (critical),
            // fp32 -> global (fire-and-forget), xp(t+2) reload (after use).
#pragma unroll
            for (int i = 0; i < 4; ++i) {
                if (!stv[i]) continue;
                const float h0 = fmaxf(accE[i][0] + accO[i][0] + xpb[e][i].x, 0.f);
                const float h1 = fmaxf(accE[i][1] + accO[i][1] + xpb[e][i].y, 0.f);
                const float h2 = fmaxf(accE[i][2] + accO[i][2] + xpb[e][i].z, 0.f);
                const float h3 = fmaxf(accE[i][3] + accO[i][3] + xpb[e][i].w, 0.f);
                half4v pk = {(_Float16)h0, (_Float16)h1, (_Float16)h2, (_Float16)h3};
                *(half4v*)&hl[cur ^ 1][m][j0a[i]] = pk;
                *(float4*)(mybase + (long long)(t + e) * HH + j0a[i]) =
                    make_float4(h0, h1, h2, h3);
                if (t + e + 2 < TT)
                    xpb[e][i] = *(const float4*)(mybase + (long long)(t + e + 2) * HH + j0a[i]);
            }

            // LDS-only fence + raw barrier: global traffic stays in flight.
            asm volatile("s_waitcnt lgkmcnt(0)" ::: "memory");
            __builtin_amdgcn_s_barrier();
            __builtin_amdgcn_sched_barrier(0);
            cur ^= 1;
        }
    }
}

// ---------------------------------------------------------------------------
// Phase 3: o[r] = sum_j W_out[j]*h[r][j] + b_out. (unchanged)
// ---------------------------------------------------------------------------
__global__ __launch_bounds__(256) void rnn_out(
    const float* __restrict__ hid, const float* __restrict__ Wout,
    const float* __restrict__ bout, float* __restrict__ out)
{
    const int wave = threadIdx.x >> 6;
    const int lane = threadIdx.x & 63;

    float wv[4];
#pragma unroll
    for (int mi = 0; mi < 4; ++mi) {
        int idx = lane + 64 * mi;
        wv[mi] = (idx < HH) ? Wout[idx] : 0.f;
    }
    const float bo = bout[0];

    const long long rbase = (long long)blockIdx.x * 64;
#pragma unroll 1
    for (int rr = wave; rr < 64; rr += 4) {
        const float* hr = hid + (rbase + rr) * HH;
        float p = 0.f;
#pragma unroll
        for (int mi = 0; mi < 4; ++mi) {
            int idx = lane + 64 * mi;
            if (idx < HH) p += wv[mi] * hr[idx];
        }
#pragma unroll
        for (int off = 32; off; off >>= 1) p += __shfl_down(p, off, 64);
        if (lane == 0) out[rbase + rr] = p + bo;
    }
}

extern "C" void kernel_launch(void* const* d_in, const int* in_sizes, int n_in,
                              void* d_out, int out_size, void* d_ws, size_t ws_size,
                              hipStream_t stream)
{
    const float* x    = (const float*)d_in[0];  // [128,1024,100]
    const float* Wih  = (const float*)d_in[1];  // [200,100]
    const float* Whh  = (const float*)d_in[2];  // [200,200]
    const float* bih  = (const float*)d_in[3];  // [200]
    const float* bhh  = (const float*)d_in[4];  // [200]
    const float* Wout = (const float*)d_in[5];  // [1,200]
    const float* bout = (const float*)d_in[6];  // [1]

    float* out = (float*)d_out;                 // [128*1024] outputs first
    float* hid = out + (long long)BB * TT;      // [128*1024*200] hiddens

    rnn_xproj<<<(BB * TT) / 128, 256, 0, stream>>>(x, Wih, bih, bhh, hid);
    rnn_recur<<<BB / MB, 256, 0, stream>>>(Whh, hid);
    rnn_out<<<(BB * TT) / 64, 256, 0, stream>>>(hid, Wout, bout, out);
}